// Round 8
// baseline (3990.324 us; speedup 1.0000x reference)
//
#include <hip/hip_runtime.h>
#include <math.h>

typedef unsigned short u16;
typedef unsigned int u32;

#define N_NODES 20000
#define MP      20480            // N padded to multiple of 1024 (128 x 8 XCD groups)
#define T_SEQ   8
#define DS      16
#define DD      8
#define E_EDGES 320000
#define HL      128
#define GH      4
#define GC      128
#define HC      512
#define EMB     64
#define KP1     160              // padded K for LSTM (136) and GAT1 (144)
#define EP      (E_EDGES + N_NODES)

typedef __attribute__((ext_vector_type(8))) short bf16x8;
typedef __attribute__((ext_vector_type(4))) float f32x4;

__device__ __forceinline__ u16 f2bf(float f) {
  u32 u = __float_as_uint(f);
  u += 0x7fff + ((u >> 16) & 1);   // RNE (inputs are finite)
  return (u16)(u >> 16);
}
__device__ __forceinline__ float bflo(u32 v) { return __uint_as_float(v << 16); }
__device__ __forceinline__ float bfhi(u32 v) { return __uint_as_float(v & 0xffff0000u); }
__device__ __forceinline__ float bf16f(u16 v) { return __uint_as_float((u32)v << 16); }

__device__ __forceinline__ void gld16(const void* g, void* l) {
  __builtin_amdgcn_global_load_lds(
      (const __attribute__((address_space(1))) void*)g,
      (__attribute__((address_space(3))) void*)l, 16, 0, 0);
}

// sum across each 16-lane row via DPP row_ror (pure VALU, no LDS pipe)
__device__ __forceinline__ float rowsum16(float p) {
  p += __int_as_float(__builtin_amdgcn_update_dpp(0, __float_as_int(p), 0x121, 0xf, 0xf, false));
  p += __int_as_float(__builtin_amdgcn_update_dpp(0, __float_as_int(p), 0x122, 0xf, 0xf, false));
  p += __int_as_float(__builtin_amdgcn_update_dpp(0, __float_as_int(p), 0x124, 0xf, 0xf, false));
  p += __int_as_float(__builtin_amdgcn_update_dpp(0, __float_as_int(p), 0x128, 0xf, 0xf, false));
  return p;
}

// ---------------------------------------------------------------------------
// bf16 MFMA GEMM: C[M,Nc] = A[M,K] @ W[Nc,K]^T (+bias).
// 128x128 tile, BK=32, double-buffered LDS (prefetch-after-barrier).
// XCD-aware swizzle (id%8 -> XCD); bf16 out via LDS-staged coalesced epilogue.
// ---------------------------------------------------------------------------
__global__ __launch_bounds__(256) void gemm_mfma(
    const u16* __restrict__ A, int lda,
    const u16* __restrict__ W, int ldw,
    const float* __restrict__ bias,
    void* __restrict__ Cout, int ldc,
    int M, int Nc, int K, int c_bf16, int gxs)
{
  __shared__ u16 smem[16384];            // dbuf staging; epilogue: C tile
  u16* Asm = smem;
  u16* Bsm = smem + 8192;

  const int tid = threadIdx.x;
  const int wave = tid >> 6, lane = tid & 63;
  const int wm = (wave >> 1) << 6, wn = (wave & 1) << 6;

  const u32 id = blockIdx.x;
  const int xcd = id & 7;
  const u32 sl = id >> 3;
  const int GXm = (1 << gxs) - 1;
  const int bn = (int)(sl & GXm) << 7;
  const int bm = (xcd + (int)((sl >> gxs) << 3)) << 7;

  f32x4 acc[4][4];
#pragma unroll
  for (int i = 0; i < 4; ++i)
#pragma unroll
    for (int j = 0; j < 4; ++j) acc[i][j] = (f32x4){0.f, 0.f, 0.f, 0.f};

  const int qr = lane >> 2;
  const int qc = (lane & 3) << 3;
  const int q0 = wave * 2, q1 = wave * 2 + 1;
  const int ra0 = bm + q0 * 16 + qr;
  const int ra1 = bm + q1 * 16 + qr;
  int rb0 = bn + q0 * 16 + qr; if (rb0 >= Nc) rb0 = Nc - 1;
  int rb1 = bn + q1 * 16 + qr; if (rb1 >= Nc) rb1 = Nc - 1;

  const u16* pa0 = A + (size_t)ra0 * lda + qc;
  const u16* pa1 = A + (size_t)ra1 * lda + qc;
  const u16* pb0 = W + (size_t)rb0 * ldw + qc;
  const u16* pb1 = W + (size_t)rb1 * ldw + qc;

  const int fm = lane & 15;
  const int fk = (lane >> 4) << 3;

  gld16(pa0, &Asm[q0 * 512]);
  gld16(pa1, &Asm[q1 * 512]);
  gld16(pb0, &Bsm[q0 * 512]);
  gld16(pb1, &Bsm[q1 * 512]);
  pa0 += 32; pa1 += 32; pb0 += 32; pb1 += 32;

  const int iters = K >> 5;
#pragma unroll 2
  for (int it = 0; it < iters; ++it) {
    const int cur = (it & 1) * 4096;
    __syncthreads();
    if (it + 1 < iters) {
      const int nxt = cur ^ 4096;
      gld16(pa0, &Asm[nxt + q0 * 512]);
      gld16(pa1, &Asm[nxt + q1 * 512]);
      gld16(pb0, &Bsm[nxt + q0 * 512]);
      gld16(pb1, &Bsm[nxt + q1 * 512]);
      pa0 += 32; pa1 += 32; pb0 += 32; pb1 += 32;
    }
    bf16x8 af[4], bfr[4];
#pragma unroll
    for (int i = 0; i < 4; ++i)
      af[i] = *(const bf16x8*)&Asm[cur + (wm + i * 16 + fm) * 32 + fk];
#pragma unroll
    for (int j = 0; j < 4; ++j)
      bfr[j] = *(const bf16x8*)&Bsm[cur + (wn + j * 16 + fm) * 32 + fk];
#pragma unroll
    for (int i = 0; i < 4; ++i)
#pragma unroll
      for (int j = 0; j < 4; ++j)
        acc[i][j] = __builtin_amdgcn_mfma_f32_16x16x32_bf16(af[i], bfr[j], acc[i][j], 0, 0, 0);
  }

  const int cn = lane & 15, cm = (lane >> 4) << 2;
  if (c_bf16) {
    __syncthreads();
#pragma unroll
    for (int j = 0; j < 4; ++j) {
      const int c = wn + j * 16 + cn;
      const float bb = bias ? bias[bn + c] : 0.f;
#pragma unroll
      for (int i = 0; i < 4; ++i) {
#pragma unroll
        for (int r = 0; r < 4; ++r)
          smem[(wm + i * 16 + cm + r) * 128 + c] = f2bf(acc[i][j][r] + bb);
      }
    }
    __syncthreads();
    u16* outc = (u16*)Cout;
#pragma unroll
    for (int k = 0; k < 8; ++k) {
      const int idx = tid + k * 256;
      const int r = idx >> 4, cc = (idx & 15) << 3;
      *(uint4*)(outc + (size_t)(bm + r) * ldc + bn + cc) = *(const uint4*)&smem[r * 128 + cc];
    }
  } else {
#pragma unroll
    for (int j = 0; j < 4; ++j) {
      const int c = bn + wn + j * 16 + cn;
      if (c >= Nc) continue;
      const float bb = bias ? bias[c] : 0.f;
#pragma unroll
      for (int i = 0; i < 4; ++i) {
#pragma unroll
        for (int r = 0; r < 4; ++r) {
          const int m = bm + wm + i * 16 + cm + r;
          if (m >= M) continue;
          ((float*)Cout)[(size_t)m * ldc + c] = acc[i][j][r] + bb;
        }
      }
    }
  }
}

// ---------------------------------------------------------------------------
// Setup / conversion kernels (once per launch; tiny)
// ---------------------------------------------------------------------------
__global__ void k_bias_sum(const float* __restrict__ b_ih,
                           const float* __restrict__ b_hh,
                           float* __restrict__ bsum) {
  int i = blockIdx.x * blockDim.x + threadIdx.x;
  if (i < 4 * HL) bsum[i] = b_ih[i] + b_hh[i];
}

__global__ void k_wcat_bf(const float* __restrict__ W_ih,
                          const float* __restrict__ W_hh,
                          u16* __restrict__ w) {
  int idx = blockIdx.x * blockDim.x + threadIdx.x;
  if (idx >= HC * KP1) return;
  int j = idx / KP1, k = idx - j * KP1;
  float v = 0.f;
  if (k < DD) v = W_ih[j * DD + k];
  else if (k < DD + HL) v = W_hh[j * HL + (k - DD)];
  w[idx] = f2bf(v);
}

__global__ void k_wlr1_bf(const float* __restrict__ Wl,
                          const float* __restrict__ Wr,
                          u16* __restrict__ w) {
  int idx = blockIdx.x * blockDim.x + threadIdx.x;
  if (idx >= 2 * HC * KP1) return;
  int j = idx / KP1, k = idx - j * KP1;
  const float* src = (j < HC) ? Wl : Wr;
  int jj = j & (HC - 1);
  float v = (k < DS + HL) ? src[jj * (DS + HL) + k] : 0.f;
  w[idx] = f2bf(v);
}

__global__ void k_wlr2_bf(const float* __restrict__ Wl,
                          const float* __restrict__ Wr,
                          u16* __restrict__ w) {
  int idx = blockIdx.x * blockDim.x + threadIdx.x;
  if (idx >= 2 * HC * HC) return;
  int j = idx >> 9, k = idx & (HC - 1);
  const float* src = (j < HC) ? Wl : Wr;
  int jj = j & (HC - 1);
  w[idx] = f2bf(src[jj * HC + k]);
}

__global__ void k_wp_bf(const float* __restrict__ Wp, u16* __restrict__ w) {
  int idx = blockIdx.x * blockDim.x + threadIdx.x;
  if (idx < EMB * HC) w[idx] = f2bf(Wp[idx]);
}

__global__ void k_pack_static(const float* __restrict__ xs, u16* __restrict__ packG1) {
  int idx = blockIdx.x * blockDim.x + threadIdx.x;
  if (idx >= N_NODES * DS) return;
  int n = idx >> 4, k = idx & 15;
  packG1[(size_t)n * KP1 + k] = f2bf(xs[idx]);
}

__global__ void k_pack_dyn(const float* __restrict__ dyn, u16* __restrict__ packXH) {
  int idx = blockIdx.x * blockDim.x + threadIdx.x;
  if (idx >= N_NODES * DD) return;
  int n = idx >> 3, k = idx & 7;
  packXH[(size_t)n * KP1 + k] = f2bf(dyn[(size_t)n * (T_SEQ * DD) + k]);
}

// LSTM pointwise; gates in bf16; writes h into both GEMM inputs + next dyn cols
__global__ void lstm_update(const u16* __restrict__ gatesb,
                            float* __restrict__ c,
                            u16* __restrict__ packXH, u16* __restrict__ packG1,
                            const float* __restrict__ dyn, int t_next) {
  int idx = blockIdx.x * blockDim.x + threadIdx.x;
  if (idx >= N_NODES * HL) return;
  int n = idx >> 7, j = idx & 127;
  const u16* g = gatesb + (size_t)n * HC;
  float gi = bf16f(g[j]), gf = bf16f(g[j + 128]);
  float gg = bf16f(g[j + 256]), go = bf16f(g[j + 384]);
  float si = 1.f / (1.f + __expf(-gi));
  float sf = 1.f / (1.f + __expf(-gf));
  float so = 1.f / (1.f + __expf(-go));
  float cn = sf * c[idx] + si * tanhf(gg);
  c[idx] = cn;
  u16 hb = f2bf(so * tanhf(cn));
  packXH[(size_t)n * KP1 + DD + j] = hb;
  packG1[(size_t)n * KP1 + DS + j] = hb;
  if (j < DD && t_next < T_SEQ)
    packXH[(size_t)n * KP1 + j] =
        f2bf(dyn[(size_t)n * (T_SEQ * DD) + t_next * DD + j]);
}

// ---------------------------------------------------------------------------
// CSR build (dst-sorted), rebuilt every launch. Entries pre-shifted (s<<11).
// ---------------------------------------------------------------------------
__global__ void k_deg(const int* __restrict__ ei, int* __restrict__ deg) {
  int e = blockIdx.x * blockDim.x + threadIdx.x;
  if (e >= EP) return;
  int d = (e < E_EDGES) ? ei[E_EDGES + e] : (e - E_EDGES);
  atomicAdd(&deg[d], 1);
}

__global__ __launch_bounds__(1024) void k_scan(const int* __restrict__ deg,
                                               int* __restrict__ rowstart) {
  __shared__ int buf[1024];
  __shared__ int carry_s;
  const int tid = threadIdx.x;
  if (tid == 0) carry_s = 0;
  __syncthreads();
  for (int base = 0; base < N_NODES; base += 1024) {
    int v = (base + tid < N_NODES) ? deg[base + tid] : 0;
    buf[tid] = v;
    __syncthreads();
    for (int off = 1; off < 1024; off <<= 1) {
      int add = (tid >= off) ? buf[tid - off] : 0;
      __syncthreads();
      buf[tid] += add;
      __syncthreads();
    }
    int incl = buf[tid];
    int carry = carry_s;
    if (base + tid < N_NODES) rowstart[base + tid] = carry + incl - v;
    __syncthreads();
    if (tid == 1023) carry_s = carry + incl;
    __syncthreads();
  }
  if (tid == 0) rowstart[N_NODES] = carry_s;
}

__global__ void k_fill(const int* __restrict__ ei,
                       const int* __restrict__ rowstart,
                       int* __restrict__ cursor, u32* __restrict__ csr) {
  int e = blockIdx.x * blockDim.x + threadIdx.x;
  if (e >= EP) return;
  int s, d;
  if (e < E_EDGES) { s = ei[e]; d = ei[E_EDGES + e]; }
  else             { s = d = e - E_EDGES; }
  int pos = atomicAdd(&cursor[d], 1);
  csr[rowstart[d] + pos] = (u32)s << 11;
}

// ---------------------------------------------------------------------------
// GATv2 edge softmax + aggregation v7 (= proven R6 loop + fused BN stats).
// xlr bf16 [MP,1024] (xl | xr). One wave per dst; lane = 8 channels (uint4
// gather); heads = 16-lane rows. DPP reduce; leaky via 0.6*s + 0.4*|s|.
// Epilogue accumulates per-block column sum/sumsq in LDS then 4 global
// atomics/thread into stats (replaces the separate bn_stats kernel).
// ---------------------------------------------------------------------------
__global__ __launch_bounds__(256) void gat_edge(
    const u16* __restrict__ xlr,
    const float* __restrict__ att, const float* __restrict__ bias,
    const int* __restrict__ rowstart, const u32* __restrict__ csr,
    u16* __restrict__ outb, float* __restrict__ stats)
{
  __shared__ float ssum[HC];
  __shared__ float ssq[HC];
  const int tid = threadIdx.x;
  ssum[tid] = 0.f; ssum[tid + 256] = 0.f;
  ssq[tid]  = 0.f; ssq[tid + 256]  = 0.f;
  __syncthreads();

  const int wave = tid >> 6, lane = tid & 63;
  const int d = blockIdx.x * 4 + wave;
  const int ch = lane * 8;                  // [0,512); head = lane>>4
  const uint4 vr = *(const uint4*)(xlr + (size_t)d * 1024 + 512 + ch);
  const float rxa0 = bflo(vr.x), rxa1 = bfhi(vr.x), rxa2 = bflo(vr.y), rxa3 = bfhi(vr.y);
  const float rxb0 = bflo(vr.z), rxb1 = bfhi(vr.z), rxb2 = bflo(vr.w), rxb3 = bfhi(vr.w);
  const float4 ava = *(const float4*)(att + ch);
  const float4 avb = *(const float4*)(att + ch + 4);
  const int row = rowstart[d], end = rowstart[d + 1];
  const char* __restrict__ xbase = (const char*)(xlr + ch);  // + (s<<11) bytes

  float l = 0.f;
  float a0 = 0.f, a1 = 0.f, a2 = 0.f, a3 = 0.f;
  float b0 = 0.f, b1 = 0.f, b2 = 0.f, b3 = 0.f;

#define GAT_STEP(v)                                                          \
  {                                                                          \
    const float xa0 = bflo((v).x), xa1 = bfhi((v).x);                        \
    const float xa2 = bflo((v).y), xa3 = bfhi((v).y);                        \
    const float xb0 = bflo((v).z), xb1 = bfhi((v).z);                        \
    const float xb2 = bflo((v).w), xb3 = bfhi((v).w);                        \
    const float e0 = xa0 + rxa0, e1 = xa1 + rxa1;                            \
    const float e2 = xa2 + rxa2, e3 = xa3 + rxa3;                            \
    const float f0 = xb0 + rxb0, f1 = xb1 + rxb1;                            \
    const float f2 = xb2 + rxb2, f3 = xb3 + rxb3;                            \
    float ps = e0 * ava.x;                                                   \
    ps = fmaf(e1, ava.y, ps); ps = fmaf(e2, ava.z, ps);                      \
    ps = fmaf(e3, ava.w, ps); ps = fmaf(f0, avb.x, ps);                      \
    ps = fmaf(f1, avb.y, ps); ps = fmaf(f2, avb.z, ps);                      \
    ps = fmaf(f3, avb.w, ps);                                                \
    float pa = fabsf(e0) * ava.x;                                            \
    pa = fmaf(fabsf(e1), ava.y, pa); pa = fmaf(fabsf(e2), ava.z, pa);        \
    pa = fmaf(fabsf(e3), ava.w, pa); pa = fmaf(fabsf(f0), avb.x, pa);        \
    pa = fmaf(fabsf(f1), avb.y, pa); pa = fmaf(fabsf(f2), avb.z, pa);        \
    pa = fmaf(fabsf(f3), avb.w, pa);                                         \
    float p = rowsum16(fmaf(0.6f, ps, 0.4f * pa));                           \
    const float w = __expf(p);                                               \
    l += w;                                                                  \
    a0 = fmaf(w, xa0, a0); a1 = fmaf(w, xa1, a1);                            \
    a2 = fmaf(w, xa2, a2); a3 = fmaf(w, xa3, a3);                            \
    b0 = fmaf(w, xb0, b0); b1 = fmaf(w, xb1, b1);                            \
    b2 = fmaf(w, xb2, b2); b3 = fmaf(w, xb3, b3);                            \
  }

  int i = row;
  for (; i + 3 < end; i += 4) {
    const u32 s0 = csr[i],     s1 = csr[i + 1];
    const u32 s2 = csr[i + 2], s3 = csr[i + 3];
    const uint4 v0 = *(const uint4*)(xbase + s0);
    const uint4 v1 = *(const uint4*)(xbase + s1);
    const uint4 v2 = *(const uint4*)(xbase + s2);
    const uint4 v3 = *(const uint4*)(xbase + s3);
    GAT_STEP(v0);
    GAT_STEP(v1);
    GAT_STEP(v2);
    GAT_STEP(v3);
  }
  for (; i < end; ++i) {
    const uint4 v0 = *(const uint4*)(xbase + csr[i]);
    GAT_STEP(v0);
  }
#undef GAT_STEP

  const float inv = 1.f / l;
  const float4 ba = *(const float4*)(bias + ch);
  const float4 bb = *(const float4*)(bias + ch + 4);
  const float o0 = fmaf(a0, inv, ba.x), o1 = fmaf(a1, inv, ba.y);
  const float o2 = fmaf(a2, inv, ba.z), o3 = fmaf(a3, inv, ba.w);
  const float o4 = fmaf(b0, inv, bb.x), o5 = fmaf(b1, inv, bb.y);
  const float o6 = fmaf(b2, inv, bb.z), o7 = fmaf(b3, inv, bb.w);
  uint4 ov;
  ov.x = (u32)f2bf(o0) | ((u32)f2bf(o1) << 16);
  ov.y = (u32)f2bf(o2) | ((u32)f2bf(o3) << 16);
  ov.z = (u32)f2bf(o4) | ((u32)f2bf(o5) << 16);
  ov.w = (u32)f2bf(o6) | ((u32)f2bf(o7) << 16);
  *(uint4*)(outb + (size_t)d * HC + ch) = ov;

  // fused BN stats: per-block LDS reduction (4-way wave contention max)
  atomicAdd(&ssum[ch + 0], o0); atomicAdd(&ssq[ch + 0], o0 * o0);
  atomicAdd(&ssum[ch + 1], o1); atomicAdd(&ssq[ch + 1], o1 * o1);
  atomicAdd(&ssum[ch + 2], o2); atomicAdd(&ssq[ch + 2], o2 * o2);
  atomicAdd(&ssum[ch + 3], o3); atomicAdd(&ssq[ch + 3], o3 * o3);
  atomicAdd(&ssum[ch + 4], o4); atomicAdd(&ssq[ch + 4], o4 * o4);
  atomicAdd(&ssum[ch + 5], o5); atomicAdd(&ssq[ch + 5], o5 * o5);
  atomicAdd(&ssum[ch + 6], o6); atomicAdd(&ssq[ch + 6], o6 * o6);
  atomicAdd(&ssum[ch + 7], o7); atomicAdd(&ssq[ch + 7], o7 * o7);
  __syncthreads();
  atomicAdd(&stats[tid],            ssum[tid]);
  atomicAdd(&stats[tid + 256],      ssum[tid + 256]);
  atomicAdd(&stats[HC + tid],       ssq[tid]);
  atomicAdd(&stats[HC + tid + 256], ssq[tid + 256]);
}

// ---------------------------------------------------------------------------
// BatchNorm apply (stats pre-accumulated by gat_edge) + ReLU -> bf16
// ---------------------------------------------------------------------------
__global__ void bn_apply(const u16* __restrict__ x, const float* __restrict__ stats,
                         const float* __restrict__ gamma, const float* __restrict__ beta,
                         u16* __restrict__ outb) {
  int idx = blockIdx.x * blockDim.x + threadIdx.x;
  if (idx >= N_NODES * (HC / 2)) return;
  const int cc = idx & (HC / 2 - 1);
  const int c0 = cc * 2, c1 = c0 + 1;
  const u32 v = ((const u32*)x)[idx];
  const float mean0 = stats[c0] * (1.f / N_NODES);
  const float mean1 = stats[c1] * (1.f / N_NODES);
  const float inv0 = rsqrtf(stats[HC + c0] * (1.f / N_NODES) - mean0 * mean0 + 1e-5f);
  const float inv1 = rsqrtf(stats[HC + c1] * (1.f / N_NODES) - mean1 * mean1 + 1e-5f);
  float z0 = (bflo(v) - mean0) * inv0 * gamma[c0] + beta[c0];
  float z1 = (bfhi(v) - mean1) * inv1 * gamma[c1] + beta[c1];
  z0 = z0 > 0.f ? z0 : 0.f;
  z1 = z1 > 0.f ? z1 : 0.f;
  ((u32*)outb)[idx] = (u32)f2bf(z0) | ((u32)f2bf(z1) << 16);
}

// ---------------------------------------------------------------------------
extern "C" void kernel_launch(void* const* d_in, const int* in_sizes, int n_in,
                              void* d_out, int out_size, void* d_ws, size_t ws_size,
                              hipStream_t stream) {
  const float* x_static = (const float*)d_in[0];
  const float* dyn      = (const float*)d_in[1];
  const int*   ei       = (const int*)d_in[2];
  const float* W_ih     = (const float*)d_in[3];
  const float* W_hh     = (const float*)d_in[4];
  const float* b_ih     = (const float*)d_in[5];
  const float* b_hh     = (const float*)d_in[6];
  const float* Wl1      = (const float*)d_in[7];
  const float* Wr1      = (const float*)d_in[8];
  const float* att1     = (const float*)d_in[9];
  const float* bg1      = (const float*)d_in[10];
  const float* Wl2      = (const float*)d_in[11];
  const float* Wr2      = (const float*)d_in[12];
  const float* att2     = (const float*)d_in[13];
  const float* bg2      = (const float*)d_in[14];
  const float* gamma1   = (const float*)d_in[15];
  const float* beta1    = (const float*)d_in[16];
  const float* gamma2   = (const float*)d_in[17];
  const float* beta2    = (const float*)d_in[18];
  const float* Wp       = (const float*)d_in[19];
  const float* bp       = (const float*)d_in[20];
  float* out = (float*)d_out;

  // ---- workspace carve (float units) ----
  float* ws = (float*)d_ws;
  size_t o = 0;
  float* c        = ws + o; o += (size_t)MP * HL;
  float* statsAll = ws + o; o += (size_t)T_SEQ * 4 * HC;
  float* bsum     = ws + o; o += 4 * HL;
  u16* gatesb  = (u16*)(ws + o); o += (size_t)MP * HC / 2;
  u16* packXH  = (u16*)(ws + o); o += (size_t)MP * KP1 / 2;
  u16* packG1  = (u16*)(ws + o); o += (size_t)MP * KP1 / 2;
  u16* xlr     = (u16*)(ws + o); o += (size_t)MP * 1024 / 2;
  u16* gout    = (u16*)(ws + o); o += (size_t)MP * HC / 2;
  u16* aggb    = (u16*)(ws + o); o += (size_t)MP * HC / 2;
  u16* wcat_bf = (u16*)(ws + o); o += (size_t)HC * KP1 / 2;
  u16* wlr1_bf = (u16*)(ws + o); o += (size_t)2 * HC * KP1 / 2;
  u16* wlr2_bf = (u16*)(ws + o); o += (size_t)2 * HC * HC / 2;
  u16* wp_bf   = (u16*)(ws + o); o += (size_t)EMB * HC / 2;
  int* deg      = (int*)(ws + o); o += N_NODES;
  int* cursor   = (int*)(ws + o); o += N_NODES;
  int* rowstart = (int*)(ws + o); o += N_NODES + 64;
  u32* csr      = (u32*)(ws + o); o += EP;

  // ---- per-launch init ----
  hipMemsetAsync(deg,      0, N_NODES * sizeof(int), stream);
  hipMemsetAsync(cursor,   0, N_NODES * sizeof(int), stream);
  hipMemsetAsync(statsAll, 0, (size_t)T_SEQ * 4 * HC * sizeof(float), stream);
  hipMemsetAsync(c,        0, (size_t)MP * HL * sizeof(float), stream);
  hipMemsetAsync(packXH,   0, (size_t)MP * KP1 * sizeof(u16), stream);  // h=0 + pads
  hipMemsetAsync(packG1,   0, (size_t)MP * KP1 * sizeof(u16), stream);
  hipMemsetAsync(aggb,     0, (size_t)MP * HC * sizeof(u16), stream);   // pad rows

  k_bias_sum<<<2, 256, 0, stream>>>(b_ih, b_hh, bsum);
  k_wcat_bf<<<(HC * KP1 + 255) / 256, 256, 0, stream>>>(W_ih, W_hh, wcat_bf);
  k_wlr1_bf<<<(2 * HC * KP1 + 255) / 256, 256, 0, stream>>>(Wl1, Wr1, wlr1_bf);
  k_wlr2_bf<<<(2 * HC * HC + 255) / 256, 256, 0, stream>>>(Wl2, Wr2, wlr2_bf);
  k_wp_bf<<<(EMB * HC + 255) / 256, 256, 0, stream>>>(Wp, wp_bf);
  k_pack_static<<<(N_NODES * DS + 255) / 256, 256, 0, stream>>>(x_static, packG1);
  k_pack_dyn<<<(N_NODES * DD + 255) / 256, 256, 0, stream>>>(dyn, packXH);
  k_deg<<<(EP + 255) / 256, 256, 0, stream>>>(ei, deg);
  k_scan<<<1, 1024, 0, stream>>>(deg, rowstart);
  k_fill<<<(EP + 255) / 256, 256, 0, stream>>>(ei, rowstart, cursor, csr);

  const int GY = MP / 128;                       // 160 (divisible by 8)

  for (int t = 0; t < T_SEQ; ++t) {
    float* stats = statsAll + (size_t)t * 4 * HC;

    // ---- LSTM step t ----
    gemm_mfma<<<4 * GY, 256, 0, stream>>>(packXH, KP1, wcat_bf, KP1, bsum,
                                          gatesb, HC, MP, HC, KP1, 1, 2);
    lstm_update<<<(N_NODES * HL + 255) / 256, 256, 0, stream>>>(
        gatesb, c, packXH, packG1, dyn, t + 1);

    // ---- GAT layer 1 ----
    gemm_mfma<<<8 * GY, 256, 0, stream>>>(packG1, KP1, wlr1_bf, KP1, nullptr,
                                          xlr, 1024, MP, 2 * HC, KP1, 1, 3);
    gat_edge<<<N_NODES / 4, 256, 0, stream>>>(xlr, att1, bg1, rowstart, csr,
                                              gout, stats);
    bn_apply<<<(N_NODES * HC / 2 + 255) / 256, 256, 0, stream>>>(gout, stats,
                                                                 gamma1, beta1, aggb);

    // ---- GAT layer 2 ----
    gemm_mfma<<<8 * GY, 256, 0, stream>>>(aggb, HC, wlr2_bf, HC, nullptr,
                                          xlr, 1024, MP, 2 * HC, HC, 1, 3);
    gat_edge<<<N_NODES / 4, 256, 0, stream>>>(xlr, att2, bg2, rowstart, csr,
                                              gout, stats + 2 * HC);
    bn_apply<<<(N_NODES * HC / 2 + 255) / 256, 256, 0, stream>>>(gout, stats + 2 * HC,
                                                                 gamma2, beta2, aggb);

    // ---- output projection into out[n][t][:] ----
    gemm_mfma<<<1 * GY, 256, 0, stream>>>(aggb, HC, wp_bf, HC, bp,
                                          out + t * EMB, T_SEQ * EMB,
                                          N_NODES, EMB, HC, 0, 0);
  }
}

// Round 9
// 2427.428 us; speedup vs baseline: 1.6438x; 1.6438x over previous
//
#include <hip/hip_runtime.h>
#include <math.h>

typedef unsigned short u16;
typedef unsigned int u32;

#define N_NODES 20000
#define MP      20480            // N padded to multiple of 1024 (128 x 8 XCD groups)
#define T_SEQ   8
#define DS      16
#define DD      8
#define E_EDGES 320000
#define HL      128
#define GH      4
#define GC      128
#define HC      512
#define EMB     64
#define KP1     160              // padded K for LSTM (136) and GAT1 (144)
#define EP      (E_EDGES + N_NODES)

typedef __attribute__((ext_vector_type(8))) short bf16x8;
typedef __attribute__((ext_vector_type(4))) float f32x4;

__device__ __forceinline__ u16 f2bf(float f) {
  u32 u = __float_as_uint(f);
  u += 0x7fff + ((u >> 16) & 1);   // RNE (inputs are finite)
  return (u16)(u >> 16);
}
__device__ __forceinline__ float bflo(u32 v) { return __uint_as_float(v << 16); }
__device__ __forceinline__ float bfhi(u32 v) { return __uint_as_float(v & 0xffff0000u); }
__device__ __forceinline__ float bf16f(u16 v) { return __uint_as_float((u32)v << 16); }

__device__ __forceinline__ void gld16(const void* g, void* l) {
  __builtin_amdgcn_global_load_lds(
      (const __attribute__((address_space(1))) void*)g,
      (__attribute__((address_space(3))) void*)l, 16, 0, 0);
}

// sum across each 16-lane row via DPP row_ror (pure VALU, no LDS pipe)
__device__ __forceinline__ float rowsum16(float p) {
  p += __int_as_float(__builtin_amdgcn_update_dpp(0, __float_as_int(p), 0x121, 0xf, 0xf, false));
  p += __int_as_float(__builtin_amdgcn_update_dpp(0, __float_as_int(p), 0x122, 0xf, 0xf, false));
  p += __int_as_float(__builtin_amdgcn_update_dpp(0, __float_as_int(p), 0x124, 0xf, 0xf, false));
  p += __int_as_float(__builtin_amdgcn_update_dpp(0, __float_as_int(p), 0x128, 0xf, 0xf, false));
  return p;
}

// ---------------------------------------------------------------------------
// bf16 MFMA GEMM: C[M,Nc] = A[M,K] @ W[Nc,K]^T (+bias).
// 128x128 tile, BK=32, double-buffered LDS (prefetch-after-barrier).
// XCD-aware swizzle (id%8 -> XCD); bf16 out via LDS-staged coalesced epilogue.
// ---------------------------------------------------------------------------
__global__ __launch_bounds__(256) void gemm_mfma(
    const u16* __restrict__ A, int lda,
    const u16* __restrict__ W, int ldw,
    const float* __restrict__ bias,
    void* __restrict__ Cout, int ldc,
    int M, int Nc, int K, int c_bf16, int gxs)
{
  __shared__ u16 smem[16384];            // dbuf staging; epilogue: C tile
  u16* Asm = smem;
  u16* Bsm = smem + 8192;

  const int tid = threadIdx.x;
  const int wave = tid >> 6, lane = tid & 63;
  const int wm = (wave >> 1) << 6, wn = (wave & 1) << 6;

  const u32 id = blockIdx.x;
  const int xcd = id & 7;
  const u32 sl = id >> 3;
  const int GXm = (1 << gxs) - 1;
  const int bn = (int)(sl & GXm) << 7;
  const int bm = (xcd + (int)((sl >> gxs) << 3)) << 7;

  f32x4 acc[4][4];
#pragma unroll
  for (int i = 0; i < 4; ++i)
#pragma unroll
    for (int j = 0; j < 4; ++j) acc[i][j] = (f32x4){0.f, 0.f, 0.f, 0.f};

  const int qr = lane >> 2;
  const int qc = (lane & 3) << 3;
  const int q0 = wave * 2, q1 = wave * 2 + 1;
  const int ra0 = bm + q0 * 16 + qr;
  const int ra1 = bm + q1 * 16 + qr;
  int rb0 = bn + q0 * 16 + qr; if (rb0 >= Nc) rb0 = Nc - 1;
  int rb1 = bn + q1 * 16 + qr; if (rb1 >= Nc) rb1 = Nc - 1;

  const u16* pa0 = A + (size_t)ra0 * lda + qc;
  const u16* pa1 = A + (size_t)ra1 * lda + qc;
  const u16* pb0 = W + (size_t)rb0 * ldw + qc;
  const u16* pb1 = W + (size_t)rb1 * ldw + qc;

  const int fm = lane & 15;
  const int fk = (lane >> 4) << 3;

  gld16(pa0, &Asm[q0 * 512]);
  gld16(pa1, &Asm[q1 * 512]);
  gld16(pb0, &Bsm[q0 * 512]);
  gld16(pb1, &Bsm[q1 * 512]);
  pa0 += 32; pa1 += 32; pb0 += 32; pb1 += 32;

  const int iters = K >> 5;
#pragma unroll 2
  for (int it = 0; it < iters; ++it) {
    const int cur = (it & 1) * 4096;
    __syncthreads();
    if (it + 1 < iters) {
      const int nxt = cur ^ 4096;
      gld16(pa0, &Asm[nxt + q0 * 512]);
      gld16(pa1, &Asm[nxt + q1 * 512]);
      gld16(pb0, &Bsm[nxt + q0 * 512]);
      gld16(pb1, &Bsm[nxt + q1 * 512]);
      pa0 += 32; pa1 += 32; pb0 += 32; pb1 += 32;
    }
    bf16x8 af[4], bfr[4];
#pragma unroll
    for (int i = 0; i < 4; ++i)
      af[i] = *(const bf16x8*)&Asm[cur + (wm + i * 16 + fm) * 32 + fk];
#pragma unroll
    for (int j = 0; j < 4; ++j)
      bfr[j] = *(const bf16x8*)&Bsm[cur + (wn + j * 16 + fm) * 32 + fk];
#pragma unroll
    for (int i = 0; i < 4; ++i)
#pragma unroll
      for (int j = 0; j < 4; ++j)
        acc[i][j] = __builtin_amdgcn_mfma_f32_16x16x32_bf16(af[i], bfr[j], acc[i][j], 0, 0, 0);
  }

  const int cn = lane & 15, cm = (lane >> 4) << 2;
  if (c_bf16) {
    __syncthreads();
#pragma unroll
    for (int j = 0; j < 4; ++j) {
      const int c = wn + j * 16 + cn;
      const float bb = bias ? bias[bn + c] : 0.f;
#pragma unroll
      for (int i = 0; i < 4; ++i) {
#pragma unroll
        for (int r = 0; r < 4; ++r)
          smem[(wm + i * 16 + cm + r) * 128 + c] = f2bf(acc[i][j][r] + bb);
      }
    }
    __syncthreads();
    u16* outc = (u16*)Cout;
#pragma unroll
    for (int k = 0; k < 8; ++k) {
      const int idx = tid + k * 256;
      const int r = idx >> 4, cc = (idx & 15) << 3;
      *(uint4*)(outc + (size_t)(bm + r) * ldc + bn + cc) = *(const uint4*)&smem[r * 128 + cc];
    }
  } else {
#pragma unroll
    for (int j = 0; j < 4; ++j) {
      const int c = bn + wn + j * 16 + cn;
      if (c >= Nc) continue;
      const float bb = bias ? bias[c] : 0.f;
#pragma unroll
      for (int i = 0; i < 4; ++i) {
#pragma unroll
        for (int r = 0; r < 4; ++r) {
          const int m = bm + wm + i * 16 + cm + r;
          if (m >= M) continue;
          ((float*)Cout)[(size_t)m * ldc + c] = acc[i][j][r] + bb;
        }
      }
    }
  }
}

// ---------------------------------------------------------------------------
// Setup / conversion kernels (once per launch; tiny)
// ---------------------------------------------------------------------------
__global__ void k_bias_sum(const float* __restrict__ b_ih,
                           const float* __restrict__ b_hh,
                           float* __restrict__ bsum) {
  int i = blockIdx.x * blockDim.x + threadIdx.x;
  if (i < 4 * HL) bsum[i] = b_ih[i] + b_hh[i];
}

__global__ void k_wcat_bf(const float* __restrict__ W_ih,
                          const float* __restrict__ W_hh,
                          u16* __restrict__ w) {
  int idx = blockIdx.x * blockDim.x + threadIdx.x;
  if (idx >= HC * KP1) return;
  int j = idx / KP1, k = idx - j * KP1;
  float v = 0.f;
  if (k < DD) v = W_ih[j * DD + k];
  else if (k < DD + HL) v = W_hh[j * HL + (k - DD)];
  w[idx] = f2bf(v);
}

__global__ void k_wlr1_bf(const float* __restrict__ Wl,
                          const float* __restrict__ Wr,
                          u16* __restrict__ w) {
  int idx = blockIdx.x * blockDim.x + threadIdx.x;
  if (idx >= 2 * HC * KP1) return;
  int j = idx / KP1, k = idx - j * KP1;
  const float* src = (j < HC) ? Wl : Wr;
  int jj = j & (HC - 1);
  float v = (k < DS + HL) ? src[jj * (DS + HL) + k] : 0.f;
  w[idx] = f2bf(v);
}

__global__ void k_wlr2_bf(const float* __restrict__ Wl,
                          const float* __restrict__ Wr,
                          u16* __restrict__ w) {
  int idx = blockIdx.x * blockDim.x + threadIdx.x;
  if (idx >= 2 * HC * HC) return;
  int j = idx >> 9, k = idx & (HC - 1);
  const float* src = (j < HC) ? Wl : Wr;
  int jj = j & (HC - 1);
  w[idx] = f2bf(src[jj * HC + k]);
}

__global__ void k_wp_bf(const float* __restrict__ Wp, u16* __restrict__ w) {
  int idx = blockIdx.x * blockDim.x + threadIdx.x;
  if (idx < EMB * HC) w[idx] = f2bf(Wp[idx]);
}

__global__ void k_pack_static(const float* __restrict__ xs, u16* __restrict__ packG1) {
  int idx = blockIdx.x * blockDim.x + threadIdx.x;
  if (idx >= N_NODES * DS) return;
  int n = idx >> 4, k = idx & 15;
  packG1[(size_t)n * KP1 + k] = f2bf(xs[idx]);
}

__global__ void k_pack_dyn(const float* __restrict__ dyn, u16* __restrict__ packXH) {
  int idx = blockIdx.x * blockDim.x + threadIdx.x;
  if (idx >= N_NODES * DD) return;
  int n = idx >> 3, k = idx & 7;
  packXH[(size_t)n * KP1 + k] = f2bf(dyn[(size_t)n * (T_SEQ * DD) + k]);
}

// LSTM pointwise; gates in bf16; writes h into both GEMM inputs + next dyn cols
__global__ void lstm_update(const u16* __restrict__ gatesb,
                            float* __restrict__ c,
                            u16* __restrict__ packXH, u16* __restrict__ packG1,
                            const float* __restrict__ dyn, int t_next) {
  int idx = blockIdx.x * blockDim.x + threadIdx.x;
  if (idx >= N_NODES * HL) return;
  int n = idx >> 7, j = idx & 127;
  const u16* g = gatesb + (size_t)n * HC;
  float gi = bf16f(g[j]), gf = bf16f(g[j + 128]);
  float gg = bf16f(g[j + 256]), go = bf16f(g[j + 384]);
  float si = 1.f / (1.f + __expf(-gi));
  float sf = 1.f / (1.f + __expf(-gf));
  float so = 1.f / (1.f + __expf(-go));
  float cn = sf * c[idx] + si * tanhf(gg);
  c[idx] = cn;
  u16 hb = f2bf(so * tanhf(cn));
  packXH[(size_t)n * KP1 + DD + j] = hb;
  packG1[(size_t)n * KP1 + DS + j] = hb;
  if (j < DD && t_next < T_SEQ)
    packXH[(size_t)n * KP1 + j] =
        f2bf(dyn[(size_t)n * (T_SEQ * DD) + t_next * DD + j]);
}

// ---------------------------------------------------------------------------
// CSR build (dst-sorted), rebuilt every launch. Entries pre-shifted (s<<11).
// ---------------------------------------------------------------------------
__global__ void k_deg(const int* __restrict__ ei, int* __restrict__ deg) {
  int e = blockIdx.x * blockDim.x + threadIdx.x;
  if (e >= EP) return;
  int d = (e < E_EDGES) ? ei[E_EDGES + e] : (e - E_EDGES);
  atomicAdd(&deg[d], 1);
}

__global__ __launch_bounds__(1024) void k_scan(const int* __restrict__ deg,
                                               int* __restrict__ rowstart) {
  __shared__ int buf[1024];
  __shared__ int carry_s;
  const int tid = threadIdx.x;
  if (tid == 0) carry_s = 0;
  __syncthreads();
  for (int base = 0; base < N_NODES; base += 1024) {
    int v = (base + tid < N_NODES) ? deg[base + tid] : 0;
    buf[tid] = v;
    __syncthreads();
    for (int off = 1; off < 1024; off <<= 1) {
      int add = (tid >= off) ? buf[tid - off] : 0;
      __syncthreads();
      buf[tid] += add;
      __syncthreads();
    }
    int incl = buf[tid];
    int carry = carry_s;
    if (base + tid < N_NODES) rowstart[base + tid] = carry + incl - v;
    __syncthreads();
    if (tid == 1023) carry_s = carry + incl;
    __syncthreads();
  }
  if (tid == 0) rowstart[N_NODES] = carry_s;
}

__global__ void k_fill(const int* __restrict__ ei,
                       const int* __restrict__ rowstart,
                       int* __restrict__ cursor, u32* __restrict__ csr) {
  int e = blockIdx.x * blockDim.x + threadIdx.x;
  if (e >= EP) return;
  int s, d;
  if (e < E_EDGES) { s = ei[e]; d = ei[E_EDGES + e]; }
  else             { s = d = e - E_EDGES; }
  int pos = atomicAdd(&cursor[d], 1);
  csr[rowstart[d] + pos] = (u32)s << 11;
}

// ---------------------------------------------------------------------------
// GATv2 edge softmax + aggregation (proven R6 loop, pre-shifted csr).
// xlr bf16 [MP,1024] (xl | xr). One wave per dst; lane = 8 channels (uint4
// gather); heads = 16-lane rows. DPP reduce; leaky via 0.6*s + 0.4*|s|.
// No max subtraction (scores provably small; softmax shift-invariant).
// ---------------------------------------------------------------------------
__global__ __launch_bounds__(256) void gat_edge(
    const u16* __restrict__ xlr,
    const float* __restrict__ att, const float* __restrict__ bias,
    const int* __restrict__ rowstart, const u32* __restrict__ csr,
    u16* __restrict__ outb)
{
  const int wave = threadIdx.x >> 6, lane = threadIdx.x & 63;
  const int d = blockIdx.x * 4 + wave;
  const int ch = lane * 8;                  // [0,512); head = lane>>4
  const uint4 vr = *(const uint4*)(xlr + (size_t)d * 1024 + 512 + ch);
  const float rxa0 = bflo(vr.x), rxa1 = bfhi(vr.x), rxa2 = bflo(vr.y), rxa3 = bfhi(vr.y);
  const float rxb0 = bflo(vr.z), rxb1 = bfhi(vr.z), rxb2 = bflo(vr.w), rxb3 = bfhi(vr.w);
  const float4 ava = *(const float4*)(att + ch);
  const float4 avb = *(const float4*)(att + ch + 4);
  const int row = rowstart[d], end = rowstart[d + 1];
  const char* __restrict__ xbase = (const char*)(xlr + ch);  // + (s<<11) bytes

  float l = 0.f;
  float a0 = 0.f, a1 = 0.f, a2 = 0.f, a3 = 0.f;
  float b0 = 0.f, b1 = 0.f, b2 = 0.f, b3 = 0.f;

#define GAT_STEP(v)                                                          \
  {                                                                          \
    const float xa0 = bflo((v).x), xa1 = bfhi((v).x);                        \
    const float xa2 = bflo((v).y), xa3 = bfhi((v).y);                        \
    const float xb0 = bflo((v).z), xb1 = bfhi((v).z);                        \
    const float xb2 = bflo((v).w), xb3 = bfhi((v).w);                        \
    const float e0 = xa0 + rxa0, e1 = xa1 + rxa1;                            \
    const float e2 = xa2 + rxa2, e3 = xa3 + rxa3;                            \
    const float f0 = xb0 + rxb0, f1 = xb1 + rxb1;                            \
    const float f2 = xb2 + rxb2, f3 = xb3 + rxb3;                            \
    float ps = e0 * ava.x;                                                   \
    ps = fmaf(e1, ava.y, ps); ps = fmaf(e2, ava.z, ps);                      \
    ps = fmaf(e3, ava.w, ps); ps = fmaf(f0, avb.x, ps);                      \
    ps = fmaf(f1, avb.y, ps); ps = fmaf(f2, avb.z, ps);                      \
    ps = fmaf(f3, avb.w, ps);                                                \
    float pa = fabsf(e0) * ava.x;                                            \
    pa = fmaf(fabsf(e1), ava.y, pa); pa = fmaf(fabsf(e2), ava.z, pa);        \
    pa = fmaf(fabsf(e3), ava.w, pa); pa = fmaf(fabsf(f0), avb.x, pa);        \
    pa = fmaf(fabsf(f1), avb.y, pa); pa = fmaf(fabsf(f2), avb.z, pa);        \
    pa = fmaf(fabsf(f3), avb.w, pa);                                         \
    float p = rowsum16(fmaf(0.6f, ps, 0.4f * pa));                           \
    const float w = __expf(p);                                               \
    l += w;                                                                  \
    a0 = fmaf(w, xa0, a0); a1 = fmaf(w, xa1, a1);                            \
    a2 = fmaf(w, xa2, a2); a3 = fmaf(w, xa3, a3);                            \
    b0 = fmaf(w, xb0, b0); b1 = fmaf(w, xb1, b1);                            \
    b2 = fmaf(w, xb2, b2); b3 = fmaf(w, xb3, b3);                            \
  }

  int i = row;
  for (; i + 3 < end; i += 4) {
    const u32 s0 = csr[i],     s1 = csr[i + 1];
    const u32 s2 = csr[i + 2], s3 = csr[i + 3];
    const uint4 v0 = *(const uint4*)(xbase + s0);
    const uint4 v1 = *(const uint4*)(xbase + s1);
    const uint4 v2 = *(const uint4*)(xbase + s2);
    const uint4 v3 = *(const uint4*)(xbase + s3);
    GAT_STEP(v0);
    GAT_STEP(v1);
    GAT_STEP(v2);
    GAT_STEP(v3);
  }
  for (; i < end; ++i) {
    const uint4 v0 = *(const uint4*)(xbase + csr[i]);
    GAT_STEP(v0);
  }
#undef GAT_STEP

  const float inv = 1.f / l;
  const float4 ba = *(const float4*)(bias + ch);
  const float4 bb = *(const float4*)(bias + ch + 4);
  uint4 ov;
  ov.x = (u32)f2bf(fmaf(a0, inv, ba.x)) | ((u32)f2bf(fmaf(a1, inv, ba.y)) << 16);
  ov.y = (u32)f2bf(fmaf(a2, inv, ba.z)) | ((u32)f2bf(fmaf(a3, inv, ba.w)) << 16);
  ov.z = (u32)f2bf(fmaf(b0, inv, bb.x)) | ((u32)f2bf(fmaf(b1, inv, bb.y)) << 16);
  ov.w = (u32)f2bf(fmaf(b2, inv, bb.z)) | ((u32)f2bf(fmaf(b3, inv, bb.w)) << 16);
  *(uint4*)(outb + (size_t)d * HC + ch) = ov;
}

// ---------------------------------------------------------------------------
// BatchNorm stats (bf16 input): stats[0..HC)=sum, [HC..2HC)=sumsq
// Private per-thread accumulators, one atomic per thread per quantity.
// ---------------------------------------------------------------------------
__global__ __launch_bounds__(256) void bn_stats(const u16* __restrict__ x,
                                                float* __restrict__ stats) {
  const int tid = threadIdx.x;
  const int rows_per = (N_NODES + gridDim.x - 1) / gridDim.x;
  const int r0 = blockIdx.x * rows_per;
  const int r1 = min(r0 + rows_per, N_NODES);
  const u32* xp = (const u32*)x;
  float s0 = 0.f, s1 = 0.f, q0 = 0.f, q1 = 0.f;
  for (int r = r0; r < r1; ++r) {
    const u32 v = xp[(size_t)r * 256 + tid];
    const float v0 = bflo(v), v1 = bfhi(v);
    s0 += v0; q0 += v0 * v0;
    s1 += v1; q1 += v1 * v1;
  }
  atomicAdd(&stats[2 * tid],          s0);
  atomicAdd(&stats[2 * tid + 1],      s1);
  atomicAdd(&stats[HC + 2 * tid],     q0);
  atomicAdd(&stats[HC + 2 * tid + 1], q1);
}

__global__ void bn_apply(const u16* __restrict__ x, const float* __restrict__ stats,
                         const float* __restrict__ gamma, const float* __restrict__ beta,
                         u16* __restrict__ outb) {
  int idx = blockIdx.x * blockDim.x + threadIdx.x;
  if (idx >= N_NODES * (HC / 2)) return;
  const int cc = idx & (HC / 2 - 1);
  const int c0 = cc * 2, c1 = c0 + 1;
  const u32 v = ((const u32*)x)[idx];
  const float mean0 = stats[c0] * (1.f / N_NODES);
  const float mean1 = stats[c1] * (1.f / N_NODES);
  const float inv0 = rsqrtf(stats[HC + c0] * (1.f / N_NODES) - mean0 * mean0 + 1e-5f);
  const float inv1 = rsqrtf(stats[HC + c1] * (1.f / N_NODES) - mean1 * mean1 + 1e-5f);
  float z0 = (bflo(v) - mean0) * inv0 * gamma[c0] + beta[c0];
  float z1 = (bfhi(v) - mean1) * inv1 * gamma[c1] + beta[c1];
  z0 = z0 > 0.f ? z0 : 0.f;
  z1 = z1 > 0.f ? z1 : 0.f;
  ((u32*)outb)[idx] = (u32)f2bf(z0) | ((u32)f2bf(z1) << 16);
}

// ---------------------------------------------------------------------------
extern "C" void kernel_launch(void* const* d_in, const int* in_sizes, int n_in,
                              void* d_out, int out_size, void* d_ws, size_t ws_size,
                              hipStream_t stream) {
  const float* x_static = (const float*)d_in[0];
  const float* dyn      = (const float*)d_in[1];
  const int*   ei       = (const int*)d_in[2];
  const float* W_ih     = (const float*)d_in[3];
  const float* W_hh     = (const float*)d_in[4];
  const float* b_ih     = (const float*)d_in[5];
  const float* b_hh     = (const float*)d_in[6];
  const float* Wl1      = (const float*)d_in[7];
  const float* Wr1      = (const float*)d_in[8];
  const float* att1     = (const float*)d_in[9];
  const float* bg1      = (const float*)d_in[10];
  const float* Wl2      = (const float*)d_in[11];
  const float* Wr2      = (const float*)d_in[12];
  const float* att2     = (const float*)d_in[13];
  const float* bg2      = (const float*)d_in[14];
  const float* gamma1   = (const float*)d_in[15];
  const float* beta1    = (const float*)d_in[16];
  const float* gamma2   = (const float*)d_in[17];
  const float* beta2    = (const float*)d_in[18];
  const float* Wp       = (const float*)d_in[19];
  const float* bp       = (const float*)d_in[20];
  float* out = (float*)d_out;

  // ---- workspace carve (float units) ----
  float* ws = (float*)d_ws;
  size_t o = 0;
  float* c        = ws + o; o += (size_t)MP * HL;
  float* statsAll = ws + o; o += (size_t)T_SEQ * 4 * HC;
  float* bsum     = ws + o; o += 4 * HL;
  u16* gatesb  = (u16*)(ws + o); o += (size_t)MP * HC / 2;
  u16* packXH  = (u16*)(ws + o); o += (size_t)MP * KP1 / 2;
  u16* packG1  = (u16*)(ws + o); o += (size_t)MP * KP1 / 2;
  u16* xlr     = (u16*)(ws + o); o += (size_t)MP * 1024 / 2;
  u16* gout    = (u16*)(ws + o); o += (size_t)MP * HC / 2;
  u16* aggb    = (u16*)(ws + o); o += (size_t)MP * HC / 2;
  u16* wcat_bf = (u16*)(ws + o); o += (size_t)HC * KP1 / 2;
  u16* wlr1_bf = (u16*)(ws + o); o += (size_t)2 * HC * KP1 / 2;
  u16* wlr2_bf = (u16*)(ws + o); o += (size_t)2 * HC * HC / 2;
  u16* wp_bf   = (u16*)(ws + o); o += (size_t)EMB * HC / 2;
  int* deg      = (int*)(ws + o); o += N_NODES;
  int* cursor   = (int*)(ws + o); o += N_NODES;
  int* rowstart = (int*)(ws + o); o += N_NODES + 64;
  u32* csr      = (u32*)(ws + o); o += EP;

  // ---- per-launch init ----
  hipMemsetAsync(deg,      0, N_NODES * sizeof(int), stream);
  hipMemsetAsync(cursor,   0, N_NODES * sizeof(int), stream);
  hipMemsetAsync(statsAll, 0, (size_t)T_SEQ * 4 * HC * sizeof(float), stream);
  hipMemsetAsync(c,        0, (size_t)MP * HL * sizeof(float), stream);
  hipMemsetAsync(packXH,   0, (size_t)MP * KP1 * sizeof(u16), stream);  // h=0 + pads
  hipMemsetAsync(packG1,   0, (size_t)MP * KP1 * sizeof(u16), stream);
  hipMemsetAsync(aggb,     0, (size_t)MP * HC * sizeof(u16), stream);   // pad rows

  k_bias_sum<<<2, 256, 0, stream>>>(b_ih, b_hh, bsum);
  k_wcat_bf<<<(HC * KP1 + 255) / 256, 256, 0, stream>>>(W_ih, W_hh, wcat_bf);
  k_wlr1_bf<<<(2 * HC * KP1 + 255) / 256, 256, 0, stream>>>(Wl1, Wr1, wlr1_bf);
  k_wlr2_bf<<<(2 * HC * HC + 255) / 256, 256, 0, stream>>>(Wl2, Wr2, wlr2_bf);
  k_wp_bf<<<(EMB * HC + 255) / 256, 256, 0, stream>>>(Wp, wp_bf);
  k_pack_static<<<(N_NODES * DS + 255) / 256, 256, 0, stream>>>(x_static, packG1);
  k_pack_dyn<<<(N_NODES * DD + 255) / 256, 256, 0, stream>>>(dyn, packXH);
  k_deg<<<(EP + 255) / 256, 256, 0, stream>>>(ei, deg);
  k_scan<<<1, 1024, 0, stream>>>(deg, rowstart);
  k_fill<<<(EP + 255) / 256, 256, 0, stream>>>(ei, rowstart, cursor, csr);

  const int GY = MP / 128;                       // 160 (divisible by 8)

  for (int t = 0; t < T_SEQ; ++t) {
    float* stats = statsAll + (size_t)t * 4 * HC;

    // ---- LSTM step t ----
    gemm_mfma<<<4 * GY, 256, 0, stream>>>(packXH, KP1, wcat_bf, KP1, bsum,
                                          gatesb, HC, MP, HC, KP1, 1, 2);
    lstm_update<<<(N_NODES * HL + 255) / 256, 256, 0, stream>>>(
        gatesb, c, packXH, packG1, dyn, t + 1);

    // ---- GAT layer 1 ----
    gemm_mfma<<<8 * GY, 256, 0, stream>>>(packG1, KP1, wlr1_bf, KP1, nullptr,
                                          xlr, 1024, MP, 2 * HC, KP1, 1, 3);
    gat_edge<<<N_NODES / 4, 256, 0, stream>>>(xlr, att1, bg1, rowstart, csr, gout);
    bn_stats<<<500, 256, 0, stream>>>(gout, stats);
    bn_apply<<<(N_NODES * HC / 2 + 255) / 256, 256, 0, stream>>>(gout, stats,
                                                                 gamma1, beta1, aggb);

    // ---- GAT layer 2 ----
    gemm_mfma<<<8 * GY, 256, 0, stream>>>(aggb, HC, wlr2_bf, HC, nullptr,
                                          xlr, 1024, MP, 2 * HC, HC, 1, 3);
    gat_edge<<<N_NODES / 4, 256, 0, stream>>>(xlr, att2, bg2, rowstart, csr, gout);
    bn_stats<<<500, 256, 0, stream>>>(gout, stats + 2 * HC);
    bn_apply<<<(N_NODES * HC / 2 + 255) / 256, 256, 0, stream>>>(gout, stats + 2 * HC,
                                                                 gamma2, beta2, aggb);

    // ---- output projection into out[n][t][:] ----
    gemm_mfma<<<1 * GY, 256, 0, stream>>>(aggb, HC, wp_bf, HC, bp,
                                          out + t * EMB, T_SEQ * EMB,
                                          N_NODES, EMB, HC, 0, 0);
  }
}